// Round 6
// baseline (802.562 us; speedup 1.0000x reference)
//
#include <hip/hip_runtime.h>
#include <math.h>

// Problem constants
#define DIMS   6
#define NGEO   20
#define NPHI   27
#define NEXPERT 540
#define MPTS   256
#define NTEST  1024
#define NMAT   560          // experts + baselines
#define JIT    1e-4f
#define USTRIDE 33280       // packed padded upper-triangular floats per matrix
#define L2E    1.44269504088896340736f

// Row j of U (cols j..255) starts at uoff(j); each row padded to 4-float multiple.
__device__ __forceinline__ int uoff(int j){
    int m = j >> 2, r = j & 3;
    return 1024*m - 8*m*(m-1) + r*(256 - 4*m);
}

// ---------------------------------------------------------------------------
// Kernel 1: 2-level GMM hard routing (fp64 to match np reference argmax)
// ---------------------------------------------------------------------------
__global__ __launch_bounds__(256)
void route_kernel(const float* __restrict__ Xt, const float* __restrict__ sm,
                  const float* __restrict__ ss,
                  const float* __restrict__ gm, const float* __restrict__ glv,
                  const float* __restrict__ glw,
                  const float* __restrict__ pm, const float* __restrict__ plv,
                  const float* __restrict__ plw,
                  int* __restrict__ e_idx, int* __restrict__ g_idx)
{
    int n = blockIdx.x*256 + threadIdx.x;
    if (n >= NTEST) return;
    double xs[DIMS];
    #pragma unroll
    for (int d=0; d<DIMS; d++)
        xs[d] = ((double)Xt[n*DIMS+d] - (double)sm[d]) / (double)ss[d];
    const double cst = (double)DIMS * 1.8378770664093453;  // D*log(2*pi)

    int bg = 0; double best = -1e300;
    for (int j=0; j<NGEO; j++){
        double s = 0.0;
        #pragma unroll
        for (int d=0; d<DIMS; d++){
            double lv = (double)glv[j*DIMS+d];
            double df = xs[d] - (double)gm[j*DIMS+d];
            s += lv + df*df*exp(-lv);
        }
        double lp = (double)glw[j] - 0.5*(s + cst);
        if (lp > best){ best = lp; bg = j; }
    }
    int bk = 0; best = -1e300;
    for (int k=0; k<NPHI; k++){
        double s = 0.0;
        int o = (bg*NPHI + k)*DIMS;
        #pragma unroll
        for (int d=0; d<DIMS; d++){
            double lv = (double)plv[o+d];
            double df = xs[d] - (double)pm[o+d];
            s += lv + df*df*exp(-lv);
        }
        double lp = (double)plw[bg*NPHI+k] - 0.5*(s + cst);
        if (lp > best){ best = lp; bk = k; }
    }
    e_idx[n] = bg*NPHI + bk;
    g_idx[n] = bg;
}

// ---------------------------------------------------------------------------
// Kernel 2: left-looking Cholesky, TWO adjacent columns per thread (float2),
// 128-thread blocks. Each b128 B-broadcast feeds 8 FMAs (pk_fma pairs);
// trsm Dl reads serve 2 columns. B blocks staged once per panel via
// global_load_lds (async, overlapped with build-K).
// ---------------------------------------------------------------------------
__global__ __launch_bounds__(128, 2)
void chol_kernel(const float* __restrict__ X_exp, const float* __restrict__ Y_exp,
                 const float* __restrict__ X_base, const float* __restrict__ Y_base,
                 const float* __restrict__ lls_e, const float* __restrict__ los_e,
                 const float* __restrict__ lno_e,
                 const float* __restrict__ lls_b, const float* __restrict__ los_b,
                 const float* __restrict__ lno_b,
                 float* __restrict__ Uws, float* __restrict__ Vws)
{
    __shared__ __align__(16) float Xs[256*8];   // 8 KB   train points, stride 8
    __shared__ __align__(16) float Bs[7*1024];  // 28 KB  staged B diag-col blocks
    __shared__ float Dst[32*33];                // 4.2 KB diag-col bounce
    __shared__ float Dl[32*36];                 // diag block of L
    __shared__ float Dinv[32];                  // 1/diag(L)

    int b = blockIdx.x, t = threadIdx.x;
    int w = t >> 6, lane = t & 63;

    const float *Xtr, *Ytr;
    float lls, los, lno;
    if (b < NEXPERT){
        Xtr = X_exp + b*(MPTS*DIMS); Ytr = Y_exp + b*MPTS;
        lls = lls_e[b]; los = los_e[b]; lno = lno_e[b];
    } else {
        int g = b - NEXPERT;
        Xtr = X_base + g*(MPTS*DIMS); Ytr = Y_base + g*MPTS;
        lls = lls_b[g]; los = los_b[g]; lno = lno_b[g];
    }
    float ls2 = expf(2.f*lls);
    float os  = expf(los);
    float nv  = expf(lno) + JIT;
    float cex = -0.5f*L2E/ls2;
    float* Ug = Uws + (size_t)b*USTRIDE;

    // stage X into LDS (padded stride 8; slots 6,7 never read)
    for (int i=t; i<MPTS*DIMS; i+=128){ int r=i/DIMS, d=i-r*DIMS; Xs[r*8+d]=Xtr[i]; }

    for (int j=0; j<8; j++){
        __syncthreads();   // prev panel stores visible; Bs/Dl free

        // ---- async-stage B blocks (both waves share the work) ----
        // Block i2: B[m][k] = U[32*i2+m][32*j+k]. One issue = 64 floats.
        for (int u=w; u<16*j; u+=2){
            int blk = u >> 4, e0 = (u & 15)*64;
            int m  = 2*(u & 15) + (lane >> 5);
            int kk = lane & 31;
            int ri = 32*blk + m;
            const float* gp = Ug + (uoff(ri) + 32*j + kk - ri);
            __builtin_amdgcn_global_load_lds(
                (const __attribute__((address_space(1))) void*)gp,
                (__attribute__((address_space(3))) void*)&Bs[blk*1024 + e0],
                4, 0, 0);
        }

        int len2 = 128 - 16*j;
        bool act = (t < len2);
        int c0 = 32*j + 2*t, c1 = c0 + 1;
        float2 x[32];                  // x[k] = (U[32j+k][c0], U[32j+k][c1])

        // ---- build original K entries (overlaps staging latency) ----
        if (act){
            float4 p0a = *(const float4*)&Xs[c0*8];
            float2 p0b = *(const float2*)&Xs[c0*8+4];
            float4 p1a = *(const float4*)&Xs[c1*8];
            float2 p1b = *(const float2*)&Xs[c1*8+4];
            #pragma unroll
            for (int k=0; k<32; k++){
                const float* Xr = &Xs[(32*j+k)*8];
                float4 ra = *(const float4*)Xr;
                float2 rb = *(const float2*)(Xr+4);
                float e0v=p0a.x-ra.x, e1=p0a.y-ra.y, e2=p0a.z-ra.z, e3=p0a.w-ra.w;
                float e4=p0b.x-rb.x, e5=p0b.y-rb.y;
                float dd0 = e0v*e0v+e1*e1+e2*e2+e3*e3+e4*e4+e5*e5;
                float f0=p1a.x-ra.x, f1=p1a.y-ra.y, f2=p1a.z-ra.z, f3=p1a.w-ra.w;
                float f4=p1b.x-rb.x, f5=p1b.y-rb.y;
                float dd1 = f0*f0+f1*f1+f2*f2+f3*f3+f4*f4+f5*f5;
                x[k].x = os*exp2f(cex*dd0);
                x[k].y = os*exp2f(cex*dd1);
                if (k == 2*t)   x[k].x += nv;
                if (k == 2*t+1) x[k].y += nv;
            }
        }
        __syncthreads();   // staging drained -> Bs valid

        // ---- subtract previous panels: B broadcast, 2 cols per thread ----
        if (act){
            for (int i2=0; i2<j; i2++){
                float a0[32], a1[32];
                #pragma unroll
                for (int m=0; m<32; m++){
                    int ri = 32*i2 + m;
                    const float* ap = Ug + (uoff(ri) - ri) + c0;
                    a0[m] = ap[0]; a1[m] = ap[1];
                }
                #pragma unroll 8
                for (int m=0; m<32; m++){
                    const float4* Bp = (const float4*)&Bs[i2*1024 + m*32];
                    float na0 = -a0[m], na1 = -a1[m];
                    #pragma unroll
                    for (int kk=0; kk<8; kk++){
                        float4 bb = Bp[kk];
                        x[kk*4+0].x = fmaf(bb.x, na0, x[kk*4+0].x);
                        x[kk*4+0].y = fmaf(bb.x, na1, x[kk*4+0].y);
                        x[kk*4+1].x = fmaf(bb.y, na0, x[kk*4+1].x);
                        x[kk*4+1].y = fmaf(bb.y, na1, x[kk*4+1].y);
                        x[kk*4+2].x = fmaf(bb.z, na0, x[kk*4+2].x);
                        x[kk*4+2].y = fmaf(bb.z, na1, x[kk*4+2].y);
                        x[kk*4+3].x = fmaf(bb.w, na0, x[kk*4+3].x);
                        x[kk*4+3].y = fmaf(bb.w, na1, x[kk*4+3].y);
                    }
                }
            }
        }

        // ---- diag columns -> LDS bounce ----
        if (t < 16){
            #pragma unroll
            for (int k=0; k<32; k++){
                Dst[(2*t)*33 + k]   = x[k].x;
                Dst[(2*t+1)*33 + k] = x[k].y;
            }
        }
        __syncthreads();

        // ---- diag 32x32 factor: lanes 0..31 of wave 0, shfl only ----
        if (t < 32){
            int l = t;
            float r[32];
            #pragma unroll
            for (int k=0; k<32; k++) r[k] = (k <= l) ? Dst[l*33 + k] : 0.f;
            float myinv = 1.f;
            #pragma unroll
            for (int cc=0; cc<32; cc++){
                float pivsq = __shfl(r[cc], cc);
                float inv = rsqrtf(pivsq);
                r[cc] *= inv;
                if (l == cc) myinv = inv;
                #pragma unroll
                for (int k=cc+1; k<32; k++) r[k] -= r[cc]*__shfl(r[cc], k);
            }
            Dinv[l] = myinv;
            #pragma unroll
            for (int k=0; k<32; k++){
                if (k <= l){
                    Dl[l*36 + k] = r[k];
                    Ug[uoff(32*j+k) + l - k] = r[k];   // store diag col
                }
            }
        }
        __syncthreads();                  // Dl/Dinv visible

        // ---- trsm: in-thread, 2 cols, D via LDS broadcast ----
        if (act && t >= 16){
            #pragma unroll
            for (int cc=0; cc<32; cc++){
                float dv = Dinv[cc];
                float ax = x[cc].x*dv, ay = x[cc].y*dv;
                x[cc].x = ax; x[cc].y = ay;
                #pragma unroll
                for (int k=cc+1; k<32; k++){
                    float dk = Dl[k*36 + cc];
                    x[k].x = fmaf(dk, -ax, x[k].x);
                    x[k].y = fmaf(dk, -ay, x[k].y);
                }
            }
            // ---- store both columns ----
            #pragma unroll
            for (int k=0; k<32; k++){
                int ro = uoff(32*j+k) - (32*j+k);
                Ug[ro + c0] = x[k].x;
                Ug[ro + c1] = x[k].y;
            }
        }
    }
    __syncthreads();

    // v = L^-1 y  (forward solve, wave 0 only; L columns = U rows, coalesced)
    if (t < 64){
        int l = t;
        float z[4], rd[4];
        #pragma unroll
        for (int qq2=0; qq2<4; qq2++){
            z[qq2]  = Ytr[64*qq2 + l];
            rd[qq2] = 1.f/Ug[uoff(64*qq2 + l)];
        }
        int offj = 0;
        #pragma unroll
        for (int qq2=0; qq2<4; qq2++){
            for (int j2=0; j2<64; j2++){
                int j = 64*qq2 + j2;
                float zf = __shfl(z[qq2], j2) * __shfl(rd[qq2], j2);
                if (l == j2) z[qq2] = zf;
                #pragma unroll
                for (int r=qq2; r<4; r++){
                    int dd = 64*(r-qq2) + (l - j2);
                    int dc = dd > 0 ? dd : 0;
                    float uv = Ug[offj + dc];
                    if (dd > 0) z[r] -= uv*zf;
                }
                offj += (259-j)&~3;
            }
        }
        #pragma unroll
        for (int qq2=0; qq2<4; qq2++) Vws[b*256 + 64*qq2 + l] = z[qq2];
    }
}

// ---------------------------------------------------------------------------
// Kernel 3: per-point prediction (one wave per (point, side)) + rBCM combine
// ---------------------------------------------------------------------------
__global__ __launch_bounds__(256)
void predict_kernel(const float* __restrict__ Xt,
                    const float* __restrict__ X_exp, const float* __restrict__ X_base,
                    const float* __restrict__ lls_e, const float* __restrict__ los_e,
                    const float* __restrict__ lno_e,
                    const float* __restrict__ lls_b, const float* __restrict__ los_b,
                    const float* __restrict__ lno_b,
                    const int* __restrict__ nullmask,
                    const float* __restrict__ Uws, const float* __restrict__ Vws,
                    const int* __restrict__ e_idx, const int* __restrict__ g_idx,
                    float* __restrict__ out)
{
    __shared__ float res[4][4];   // per local wave: mu, var, prior
    int lw = threadIdx.x >> 6, l = threadIdx.x & 63;
    int wt = blockIdx.x*4 + lw, n = wt >> 1, side = wt & 1;

    int bidx; const float* Xtr; float lls, los, lno;
    if (side == 0){
        int ee = e_idx[n]; bidx = ee; Xtr = X_exp + ee*(MPTS*DIMS);
        lls = lls_e[ee]; los = los_e[ee]; lno = lno_e[ee];
    } else {
        int g = g_idx[n]; bidx = NEXPERT + g; Xtr = X_base + g*(MPTS*DIMS);
        lls = lls_b[g]; los = los_b[g]; lno = lno_b[g];
    }
    float ls2 = expf(2.f*lls), os = expf(los), nv = expf(lno) + JIT;
    float c1 = -0.5f*L2E/ls2;
    float xt[DIMS];
    #pragma unroll
    for (int d=0; d<DIMS; d++) xt[d] = Xt[n*DIMS + d];

    const float* Ug = Uws + (size_t)bidx*USTRIDE;
    const float* vv = Vws + bidx*256;

    // k* into registers (rows 64q+l), plus diag reciprocals
    float z[4], rd[4];
    #pragma unroll
    for (int q=0; q<4; q++){
        int m = 64*q + l;
        float d2 = 0.f;
        #pragma unroll
        for (int d=0; d<DIMS; d++){ float df = xt[d]-Xtr[m*DIMS+d]; d2 += df*df; }
        z[q]  = os*exp2f(c1*d2);
        rd[q] = 1.f/Ug[uoff(m)];
    }
    // w = L^-1 k*  (forward solve; L columns = U rows, coalesced loads)
    int offj = 0;
    #pragma unroll
    for (int q=0; q<4; q++){
        #pragma unroll 4
        for (int j2=0; j2<64; j2++){
            int j = 64*q + j2;
            float zf = __shfl(z[q], j2) * __shfl(rd[q], j2);
            if (l == j2) z[q] = zf;
            #pragma unroll
            for (int r=q; r<4; r++){
                int dd = 64*(r-q) + (l - j2);
                int dc = dd > 0 ? dd : 0;
                float uv = Ug[offj + dc];
                if (dd > 0) z[r] -= uv*zf;
            }
            offj += (259-j)&~3;
        }
    }
    // q = w.w ; mu = w.v
    float qq = 0.f, mu = 0.f;
    #pragma unroll
    for (int q=0; q<4; q++){ qq += z[q]*z[q]; mu += z[q]*vv[64*q + l]; }
    #pragma unroll
    for (int o=32; o>0; o>>=1){ qq += __shfl_xor(qq, o); mu += __shfl_xor(mu, o); }
    if (l == 0){
        res[lw][0] = mu;
        res[lw][1] = fmaxf(os - qq, JIT) + nv;   // predictive var incl noise
        res[lw][2] = os + nv;                    // prior
    }
    __syncthreads();
    if (threadIdx.x < 2){
        int pp = threadIdx.x, n2 = blockIdx.x*2 + pp;
        float mu_e = res[2*pp][0],   var_e = res[2*pp][1],   pr_e = res[2*pp][2];
        float mu_b = res[2*pp+1][0], var_b = res[2*pp+1][1], pr_b = res[2*pp+1][2];
        int ee = e_idx[n2];
        float be = (nullmask[ee] == 0) ? 0.f
                 : fmaxf(0.5f*(logf(pr_e) - logf(var_e)), 0.f);
        float bb = fmaxf(0.5f*(logf(pr_b) - logf(var_b)), 0.f);
        float prec = be/var_e + bb/var_b + (1.f - be - bb)/pr_b;
        prec = fmaxf(prec, 1e-6f);
        out[n2]        = (be*mu_e/var_e + bb*mu_b/var_b)/prec;
        out[NTEST + n2] = 1.f/prec;
    }
}

// ---------------------------------------------------------------------------
extern "C" void kernel_launch(void* const* d_in, const int* in_sizes, int n_in,
                              void* d_out, int out_size, void* d_ws, size_t ws_size,
                              hipStream_t stream)
{
    const float* X_test  = (const float*)d_in[0];
    const float* X_exp   = (const float*)d_in[1];
    const float* Y_exp   = (const float*)d_in[2];
    const float* X_base  = (const float*)d_in[3];
    const float* Y_base  = (const float*)d_in[4];
    const float* lls_e   = (const float*)d_in[5];
    const float* los_e   = (const float*)d_in[6];
    const float* lno_e   = (const float*)d_in[7];
    const float* lls_b   = (const float*)d_in[8];
    const float* los_b   = (const float*)d_in[9];
    const float* lno_b   = (const float*)d_in[10];
    const float* sm      = (const float*)d_in[11];
    const float* ss      = (const float*)d_in[12];
    const float* gm      = (const float*)d_in[13];
    const float* glv     = (const float*)d_in[14];
    const float* glw     = (const float*)d_in[15];
    const float* pm      = (const float*)d_in[16];
    const float* plv     = (const float*)d_in[17];
    const float* plw     = (const float*)d_in[18];
    const int*   nmask   = (const int*)d_in[19];

    float* Uws = (float*)d_ws;                       // NMAT*USTRIDE floats (74.5 MB)
    float* Vws = Uws + (size_t)NMAT*USTRIDE;         // NMAT*256 floats
    int*   e_idx = (int*)(Vws + (size_t)NMAT*256);   // NTEST ints
    int*   g_idx = e_idx + NTEST;                    // NTEST ints
    float* out = (float*)d_out;

    route_kernel<<<dim3(NTEST/256), dim3(256), 0, stream>>>(
        X_test, sm, ss, gm, glv, glw, pm, plv, plw, e_idx, g_idx);
    chol_kernel<<<dim3(NMAT), dim3(128), 0, stream>>>(
        X_exp, Y_exp, X_base, Y_base,
        lls_e, los_e, lno_e, lls_b, los_b, lno_b, Uws, Vws);
    predict_kernel<<<dim3(NTEST/2), dim3(256), 0, stream>>>(
        X_test, X_exp, X_base,
        lls_e, los_e, lno_e, lls_b, los_b, lno_b,
        nmask, Uws, Vws, e_idx, g_idx, out);
}

// Round 7
// 502.898 us; speedup vs baseline: 1.5959x; 1.5959x over previous
//
#include <hip/hip_runtime.h>
#include <math.h>

// Problem constants
#define DIMS   6
#define NGEO   20
#define NPHI   27
#define NEXPERT 540
#define MPTS   256
#define NTEST  1024
#define NMAT   560          // experts + baselines
#define JIT    1e-4f
#define USTRIDE 33280       // packed padded upper-triangular floats per matrix
#define L2E    1.44269504088896340736f

// Row j of U (cols j..255) starts at uoff(j); each row padded to 4-float multiple.
__device__ __forceinline__ int uoff(int j){
    int m = j >> 2, r = j & 3;
    return 1024*m - 8*m*(m-1) + r*(256 - 4*m);
}

// ---------------------------------------------------------------------------
// Kernel 0: zero the needed-mask (ws is poisoned 0xAA before each launch)
// ---------------------------------------------------------------------------
__global__ __launch_bounds__(1024)
void zero_kernel(int* __restrict__ needed){
    int t = threadIdx.x;
    if (t < NMAT) needed[t] = 0;
}

// ---------------------------------------------------------------------------
// Kernel 1: 2-level GMM hard routing (fp64 to match np reference argmax)
//           + mark routed non-null experts as needed
// ---------------------------------------------------------------------------
__global__ __launch_bounds__(256)
void route_kernel(const float* __restrict__ Xt, const float* __restrict__ sm,
                  const float* __restrict__ ss,
                  const float* __restrict__ gm, const float* __restrict__ glv,
                  const float* __restrict__ glw,
                  const float* __restrict__ pm, const float* __restrict__ plv,
                  const float* __restrict__ plw,
                  const int* __restrict__ nullmask,
                  int* __restrict__ e_idx, int* __restrict__ g_idx,
                  int* __restrict__ needed)
{
    int n = blockIdx.x*256 + threadIdx.x;
    if (n >= NTEST) return;
    double xs[DIMS];
    #pragma unroll
    for (int d=0; d<DIMS; d++)
        xs[d] = ((double)Xt[n*DIMS+d] - (double)sm[d]) / (double)ss[d];
    const double cst = (double)DIMS * 1.8378770664093453;  // D*log(2*pi)

    int bg = 0; double best = -1e300;
    for (int j=0; j<NGEO; j++){
        double s = 0.0;
        #pragma unroll
        for (int d=0; d<DIMS; d++){
            double lv = (double)glv[j*DIMS+d];
            double df = xs[d] - (double)gm[j*DIMS+d];
            s += lv + df*df*exp(-lv);
        }
        double lp = (double)glw[j] - 0.5*(s + cst);
        if (lp > best){ best = lp; bg = j; }
    }
    int bk = 0; best = -1e300;
    for (int k=0; k<NPHI; k++){
        double s = 0.0;
        int o = (bg*NPHI + k)*DIMS;
        #pragma unroll
        for (int d=0; d<DIMS; d++){
            double lv = (double)plv[o+d];
            double df = xs[d] - (double)pm[o+d];
            s += lv + df*df*exp(-lv);
        }
        double lp = (double)plw[bg*NPHI+k] - 0.5*(s + cst);
        if (lp > best){ best = lp; bk = k; }
    }
    int e = bg*NPHI + bk;
    e_idx[n] = e;
    g_idx[n] = bg;
    if (nullmask[e] != 0) needed[e] = 1;   // benign race: same value
}

// ---------------------------------------------------------------------------
// Kernel 1b: compact needed matrices into a worklist (single block)
// ---------------------------------------------------------------------------
__global__ __launch_bounds__(1024)
void compact_kernel(const int* __restrict__ needed,
                    int* __restrict__ list, int* __restrict__ cnt)
{
    __shared__ int s[1024];
    int t = threadIdx.x;
    int nd = 0;
    if (t < NEXPERT) nd = needed[t];
    else if (t < NMAT) nd = 1;             // baselines always needed
    s[t] = nd;
    __syncthreads();
    // Hillis-Steele inclusive scan
    for (int off=1; off<1024; off<<=1){
        int v = (t >= off) ? s[t-off] : 0;
        __syncthreads();
        s[t] += v;
        __syncthreads();
    }
    if (nd) list[s[t]-1] = t;
    if (t == NMAT-1) cnt[0] = s[t];
}

// ---------------------------------------------------------------------------
// Kernel 2: left-looking Cholesky (R5 structure), worklist-indexed with
// early-exit: only routed non-null experts + baselines are factored.
// ---------------------------------------------------------------------------
__global__ __launch_bounds__(256, 3)
void chol_kernel(const float* __restrict__ X_exp, const float* __restrict__ Y_exp,
                 const float* __restrict__ X_base, const float* __restrict__ Y_base,
                 const float* __restrict__ lls_e, const float* __restrict__ los_e,
                 const float* __restrict__ lno_e,
                 const float* __restrict__ lls_b, const float* __restrict__ los_b,
                 const float* __restrict__ lno_b,
                 const int* __restrict__ list, const int* __restrict__ cnt,
                 float* __restrict__ Uws, float* __restrict__ Vws)
{
    if (blockIdx.x >= cnt[0]) return;      // early-exit: not needed this run
    int mat = list[blockIdx.x];

    __shared__ __align__(16) float Xs[256*8];   // 8 KB   train points, stride 8
    __shared__ __align__(16) float Bs[7*1024];  // 28 KB  staged B diag-col blocks
    __shared__ float Dl[32*36];                 // diag block of L
    __shared__ float Dinv[32];                  // 1/diag(L)

    int t = threadIdx.x;
    int w = t >> 6, lane = t & 63;
    int q = (w + blockIdx.x) & 3;               // column chunk for this wave
    int c = 64*q + lane;                        // owned column

    const float *Xtr, *Ytr;
    float lls, los, lno;
    if (mat < NEXPERT){
        Xtr = X_exp + mat*(MPTS*DIMS); Ytr = Y_exp + mat*MPTS;
        lls = lls_e[mat]; los = los_e[mat]; lno = lno_e[mat];
    } else {
        int g = mat - NEXPERT;
        Xtr = X_base + g*(MPTS*DIMS); Ytr = Y_base + g*MPTS;
        lls = lls_b[g]; los = los_b[g]; lno = lno_b[g];
    }
    float ls2 = expf(2.f*lls);
    float os  = expf(los);
    float nv  = expf(lno) + JIT;
    float c1  = -0.5f*L2E/ls2;
    float* Ug = Uws + (size_t)mat*USTRIDE;

    // stage X into LDS (padded stride 8; slots 6,7 never read)
    for (int i=t; i<MPTS*DIMS; i+=256){ int r=i/DIMS, d=i-r*DIMS; Xs[r*8+d]=Xtr[i]; }

    for (int j=0; j<8; j++){
        __syncthreads();   // prev panel's Bs reads done + stores drained

        // ---- async-stage B blocks for this panel (all waves) ----
        for (int i2=0; i2<j; i2++){
            #pragma unroll
            for (int rr=0; rr<4; rr++){
                int e0 = 64*(4*w + rr);
                int m  = (e0 + lane) >> 5;
                int kk = lane & 31;
                int r  = 32*i2 + m;
                const float* gp = Ug + (uoff(r) + 32*j + kk - r);
                __builtin_amdgcn_global_load_lds(
                    (const __attribute__((address_space(1))) void*)gp,
                    (__attribute__((address_space(3))) void*)&Bs[i2*1024 + e0],
                    4, 0, 0);
            }
        }

        int l = c - 32*j;                // diag-local index of owned column
        bool act = (l >= 0);
        float x[32];                     // x[k] = U[32j+k][c]

        // ---- build original K entries (overlaps staging latency) ----
        if (act){
            float4 xa = *(const float4*)&Xs[c*8];
            float2 xb = *(const float2*)&Xs[c*8+4];
            #pragma unroll
            for (int k=0; k<32; k++){
                const float* Xr = &Xs[(32*j+k)*8];
                float4 ra = *(const float4*)Xr;
                float2 rb = *(const float2*)(Xr+4);
                float d0=xa.x-ra.x, d1=xa.y-ra.y, d2v=xa.z-ra.z, d3=xa.w-ra.w;
                float d4=xb.x-rb.x, d5=xb.y-rb.y;
                float dd = d0*d0+d1*d1+d2v*d2v+d3*d3+d4*d4+d5*d5;
                float val = os*exp2f(c1*dd);
                if (k == l) val += nv;   // diagonal
                x[k] = val;
            }
        }
        __syncthreads();   // staging drained (vmcnt 0) -> Bs valid

        // ---- subtract previous panels: B broadcast from LDS, a coalesced ----
        if (act){
            for (int i2=0; i2<j; i2++){
                float a[32];
                #pragma unroll
                for (int m=0; m<32; m++){
                    int ri = 32*i2 + m;
                    a[m] = Ug[uoff(ri) + c - ri];     // U[ri][c]
                }
                #pragma unroll 8
                for (int m=0; m<32; m++){
                    const float4* Bp = (const float4*)&Bs[i2*1024 + m*32];
                    float nam = -a[m];
                    #pragma unroll
                    for (int kk=0; kk<8; kk++){
                        float4 bb = Bp[kk];           // broadcast, conflict-free
                        x[kk*4+0] = fmaf(bb.x, nam, x[kk*4+0]);
                        x[kk*4+1] = fmaf(bb.y, nam, x[kk*4+1]);
                        x[kk*4+2] = fmaf(bb.z, nam, x[kk*4+2]);
                        x[kk*4+3] = fmaf(bb.w, nam, x[kk*4+3]);
                    }
                }
            }
        }

        // ---- diag 32x32 factor: owning half-wave, shfl only ----
        if (l >= 0 && l < 32){
            int lb = 32*(j & 1);          // lane base of the diag group
            float r[32];
            #pragma unroll
            for (int k=0; k<32; k++) r[k] = (k <= l) ? x[k] : 0.f;
            float myinv = 1.f;
            #pragma unroll
            for (int cc=0; cc<32; cc++){
                float pivsq = __shfl(r[cc], lb + cc);
                float inv = rsqrtf(pivsq);
                r[cc] *= inv;
                if (l == cc) myinv = inv;
                #pragma unroll
                for (int k=cc+1; k<32; k++) r[k] -= r[cc]*__shfl(r[cc], lb + k);
            }
            Dinv[l] = myinv;
            #pragma unroll
            for (int k=0; k<32; k++){
                if (k <= l) Dl[l*36 + k] = r[k];
                x[k] = r[k];
            }
        }
        __syncthreads();                  // Dl/Dinv visible
        // ---- trsm: in-thread, D via LDS broadcast ----
        if (l >= 32){
            #pragma unroll
            for (int cc=0; cc<32; cc++){
                float a = x[cc]*Dinv[cc];
                x[cc] = a;
                #pragma unroll
                for (int k=cc+1; k<32; k++)
                    x[k] -= Dl[k*36 + cc]*a;
            }
        }
        // ---- store panel column to global (once) ----
        if (act){
            #pragma unroll
            for (int k=0; k<32; k++){
                if (l >= k) Ug[uoff(32*j+k) + l - k] = x[k];
            }
        }
    }
    __syncthreads();

    // v = L^-1 y  (forward solve, wave 0 only; L columns = U rows, coalesced)
    if (t < 64){
        int l = t;
        float z[4], rd[4];
        #pragma unroll
        for (int qq2=0; qq2<4; qq2++){
            z[qq2]  = Ytr[64*qq2 + l];
            rd[qq2] = 1.f/Ug[uoff(64*qq2 + l)];
        }
        int offj = 0;
        #pragma unroll
        for (int qq2=0; qq2<4; qq2++){
            for (int j2=0; j2<64; j2++){
                int j = 64*qq2 + j2;
                float zf = __shfl(z[qq2], j2) * __shfl(rd[qq2], j2);
                if (l == j2) z[qq2] = zf;
                #pragma unroll
                for (int r=qq2; r<4; r++){
                    int dd = 64*(r-qq2) + (l - j2);
                    int dc = dd > 0 ? dd : 0;
                    float uv = Ug[offj + dc];
                    if (dd > 0) z[r] -= uv*zf;
                }
                offj += (259-j)&~3;
            }
        }
        #pragma unroll
        for (int qq2=0; qq2<4; qq2++) Vws[mat*256 + 64*qq2 + l] = z[qq2];
    }
}

// ---------------------------------------------------------------------------
// Kernel 3: per-point prediction (one wave per (point, side)) + rBCM combine.
// Null experts skip the solve (var<-prior => beta_e=0, no poisoned-U reads).
// ---------------------------------------------------------------------------
__global__ __launch_bounds__(256)
void predict_kernel(const float* __restrict__ Xt,
                    const float* __restrict__ X_exp, const float* __restrict__ X_base,
                    const float* __restrict__ lls_e, const float* __restrict__ los_e,
                    const float* __restrict__ lno_e,
                    const float* __restrict__ lls_b, const float* __restrict__ los_b,
                    const float* __restrict__ lno_b,
                    const int* __restrict__ nullmask,
                    const float* __restrict__ Uws, const float* __restrict__ Vws,
                    const int* __restrict__ e_idx, const int* __restrict__ g_idx,
                    float* __restrict__ out)
{
    __shared__ float res[4][4];   // per local wave: mu, var, prior
    int lw = threadIdx.x >> 6, l = threadIdx.x & 63;
    int wt = blockIdx.x*4 + lw, n = wt >> 1, side = wt & 1;

    int bidx; const float* Xtr; float lls, los, lno;
    bool isnull = false;
    if (side == 0){
        int ee = e_idx[n]; bidx = ee; Xtr = X_exp + ee*(MPTS*DIMS);
        lls = lls_e[ee]; los = los_e[ee]; lno = lno_e[ee];
        isnull = (nullmask[ee] == 0);
    } else {
        int g = g_idx[n]; bidx = NEXPERT + g; Xtr = X_base + g*(MPTS*DIMS);
        lls = lls_b[g]; los = los_b[g]; lno = lno_b[g];
    }
    float ls2 = expf(2.f*lls), os = expf(los), nv = expf(lno) + JIT;
    float c1 = -0.5f*L2E/ls2;

    if (!isnull){   // wave-uniform branch
        float xt[DIMS];
        #pragma unroll
        for (int d=0; d<DIMS; d++) xt[d] = Xt[n*DIMS + d];

        const float* Ug = Uws + (size_t)bidx*USTRIDE;
        const float* vv = Vws + bidx*256;

        // k* into registers (rows 64q+l), plus diag reciprocals
        float z[4], rd[4];
        #pragma unroll
        for (int q=0; q<4; q++){
            int m = 64*q + l;
            float d2 = 0.f;
            #pragma unroll
            for (int d=0; d<DIMS; d++){ float df = xt[d]-Xtr[m*DIMS+d]; d2 += df*df; }
            z[q]  = os*exp2f(c1*d2);
            rd[q] = 1.f/Ug[uoff(m)];
        }
        // w = L^-1 k*  (forward solve; L columns = U rows, coalesced loads)
        int offj = 0;
        #pragma unroll
        for (int q=0; q<4; q++){
            #pragma unroll 4
            for (int j2=0; j2<64; j2++){
                int j = 64*q + j2;
                float zf = __shfl(z[q], j2) * __shfl(rd[q], j2);
                if (l == j2) z[q] = zf;
                #pragma unroll
                for (int r=q; r<4; r++){
                    int dd = 64*(r-q) + (l - j2);
                    int dc = dd > 0 ? dd : 0;
                    float uv = Ug[offj + dc];
                    if (dd > 0) z[r] -= uv*zf;
                }
                offj += (259-j)&~3;
            }
        }
        // q = w.w ; mu = w.v
        float qq = 0.f, mu = 0.f;
        #pragma unroll
        for (int q=0; q<4; q++){ qq += z[q]*z[q]; mu += z[q]*vv[64*q + l]; }
        #pragma unroll
        for (int o=32; o>0; o>>=1){ qq += __shfl_xor(qq, o); mu += __shfl_xor(mu, o); }
        if (l == 0){
            res[lw][0] = mu;
            res[lw][1] = fmaxf(os - qq, JIT) + nv;   // predictive var incl noise
            res[lw][2] = os + nv;                    // prior
        }
    } else {
        if (l == 0){
            res[lw][0] = 0.f;
            res[lw][1] = os + nv;    // var = prior -> beta_e = 0, no NaN
            res[lw][2] = os + nv;
        }
    }
    __syncthreads();
    if (threadIdx.x < 2){
        int pp = threadIdx.x, n2 = blockIdx.x*2 + pp;
        float mu_e = res[2*pp][0],   var_e = res[2*pp][1],   pr_e = res[2*pp][2];
        float mu_b = res[2*pp+1][0], var_b = res[2*pp+1][1], pr_b = res[2*pp+1][2];
        int ee = e_idx[n2];
        float be = (nullmask[ee] == 0) ? 0.f
                 : fmaxf(0.5f*(logf(pr_e) - logf(var_e)), 0.f);
        float bb = fmaxf(0.5f*(logf(pr_b) - logf(var_b)), 0.f);
        float prec = be/var_e + bb/var_b + (1.f - be - bb)/pr_b;
        prec = fmaxf(prec, 1e-6f);
        out[n2]        = (be*mu_e/var_e + bb*mu_b/var_b)/prec;
        out[NTEST + n2] = 1.f/prec;
    }
}

// ---------------------------------------------------------------------------
extern "C" void kernel_launch(void* const* d_in, const int* in_sizes, int n_in,
                              void* d_out, int out_size, void* d_ws, size_t ws_size,
                              hipStream_t stream)
{
    const float* X_test  = (const float*)d_in[0];
    const float* X_exp   = (const float*)d_in[1];
    const float* Y_exp   = (const float*)d_in[2];
    const float* X_base  = (const float*)d_in[3];
    const float* Y_base  = (const float*)d_in[4];
    const float* lls_e   = (const float*)d_in[5];
    const float* los_e   = (const float*)d_in[6];
    const float* lno_e   = (const float*)d_in[7];
    const float* lls_b   = (const float*)d_in[8];
    const float* los_b   = (const float*)d_in[9];
    const float* lno_b   = (const float*)d_in[10];
    const float* sm      = (const float*)d_in[11];
    const float* ss      = (const float*)d_in[12];
    const float* gm      = (const float*)d_in[13];
    const float* glv     = (const float*)d_in[14];
    const float* glw     = (const float*)d_in[15];
    const float* pm      = (const float*)d_in[16];
    const float* plv     = (const float*)d_in[17];
    const float* plw     = (const float*)d_in[18];
    const int*   nmask   = (const int*)d_in[19];

    float* Uws = (float*)d_ws;                       // NMAT*USTRIDE floats (74.5 MB)
    float* Vws = Uws + (size_t)NMAT*USTRIDE;         // NMAT*256 floats
    int*   e_idx  = (int*)(Vws + (size_t)NMAT*256);  // NTEST
    int*   g_idx  = e_idx + NTEST;                   // NTEST
    int*   needed = g_idx + NTEST;                   // NMAT
    int*   list   = needed + NMAT;                   // NMAT
    int*   cnt    = list + NMAT;                     // 1
    float* out = (float*)d_out;

    zero_kernel<<<dim3(1), dim3(1024), 0, stream>>>(needed);
    route_kernel<<<dim3(NTEST/256), dim3(256), 0, stream>>>(
        X_test, sm, ss, gm, glv, glw, pm, plv, plw, nmask, e_idx, g_idx, needed);
    compact_kernel<<<dim3(1), dim3(1024), 0, stream>>>(needed, list, cnt);
    chol_kernel<<<dim3(NMAT), dim3(256), 0, stream>>>(
        X_exp, Y_exp, X_base, Y_base,
        lls_e, los_e, lno_e, lls_b, los_b, lno_b, list, cnt, Uws, Vws);
    predict_kernel<<<dim3(NTEST/2), dim3(256), 0, stream>>>(
        X_test, X_exp, X_base,
        lls_e, los_e, lno_e, lls_b, los_b, lno_b,
        nmask, Uws, Vws, e_idx, g_idx, out);
}